// Round 2
// baseline (1028.612 us; speedup 1.0000x reference)
//
#include <hip/hip_runtime.h>
#include <hip/hip_bf16.h>

// PointerNetwork: B=4096, L=10, IN=8, H=512, W=512. fp32 in/out, ws=256MiB.
// log_softmax over size-1 axes => hi==he==0. Surviving compute:
//   enc GRU, ew3 = h_enc @ w3^T, dec GRU, a4 = h_dec @ w4^T,
//   out_seq = tanh(ew3+a4)@v2, out_ori = h_dec @ wori[:,H:2H]^T + bori.
// Round 8: single persistent gru_chain kernel (256 blocks x 512 thr, 80KB
// dynamic LDS): all 20 GRU steps in one dispatch; h fp32 in REGISTERS across
// steps; dec xg in registers (loaded once); 8-block group barrier w/
// threadfence between steps (no launch gaps, no h HBM roundtrip).
// out_seq_all: conflict-free contiguous-quarter LDS reads + a-reg reuse.

#define B_   4096
#define L_   10
#define IN_  8
#define H_   512
#define H3_  1536
#define W_   512
#define ORI_BASE (B_ * L_ * L_)   // 409600

typedef __attribute__((ext_vector_type(8))) short s8v;
typedef __attribute__((ext_vector_type(4))) short s4v;
typedef __attribute__((ext_vector_type(4))) float f4v;

#define LOG2E  1.4426950408889634f
#define LOG2E2 2.8853900817779268f

__device__ __forceinline__ float sig_fast(float x) {
  float e = __builtin_amdgcn_exp2f(-x * LOG2E);
  return __builtin_amdgcn_rcpf(1.f + e);
}
__device__ __forceinline__ float tanh_fast(float x) {
  float e = __builtin_amdgcn_exp2f(x * LOG2E2);
  return 1.f - 2.f * __builtin_amdgcn_rcpf(e + 1.f);
}
__device__ __forceinline__ short f2bf(float f) {
  __hip_bfloat16 h = __float2bfloat16(f);
  return __builtin_bit_cast(short, h);
}
__device__ __forceinline__ float bf2f(short s) {
  __hip_bfloat16 h = __builtin_bit_cast(__hip_bfloat16, s);
  return __bfloat162float(h);
}
__device__ __forceinline__ void stc(float* p, float v) { *p = v; }
__device__ __forceinline__ void stc(short* p, float v) { *p = f2bf(v); }

__global__ __launch_bounds__(256) void f2bf_k(const float* __restrict__ src,
                                              short* __restrict__ dst, int n)
{
  int i = blockIdx.x * 256 + threadIdx.x;
  if (i < n) dst[i] = f2bf(src[i]);
}

// Fold embedding into encoder input weight. One wave per g-row (1536 waves).
__global__ __launch_bounds__(256) void build_wc(
    const float* __restrict__ enc_wih, const float* __restrict__ emb_w,
    const float* __restrict__ emb_b, const float* __restrict__ enc_bih,
    float* __restrict__ Wc, float* __restrict__ bc)
{
  __shared__ float se[H_ * IN_];   // 16 KB
  __shared__ float sb[H_];         // 2 KB
  const int tid = threadIdx.x;
  for (int i = tid; i < H_ * IN_; i += 256) se[i] = emb_w[i];
  for (int i = tid; i < H_; i += 256) sb[i] = emb_b[i];
  __syncthreads();
  int g = (blockIdx.x * 256 + tid) >> 6;
  int lane = tid & 63;
  const float* wr = enc_wih + (long)g * H_ + lane * 8;
  float w8[8];
#pragma unroll
  for (int j = 0; j < 8; ++j) w8[j] = wr[j];
  float acc[9] = {};
#pragma unroll
  for (int kk = 0; kk < 8; ++kk) {
    int k = lane * 8 + kk;
#pragma unroll
    for (int j = 0; j < 8; ++j) acc[j] += w8[kk] * se[k * IN_ + j];
    acc[8] += w8[kk] * sb[k];
  }
#pragma unroll
  for (int j = 0; j < 9; ++j)
#pragma unroll
    for (int off = 32; off; off >>= 1) acc[j] += __shfl_down(acc[j], off, 64);
  if (lane == 0) {
#pragma unroll
    for (int j = 0; j < 8; ++j) Wc[g * IN_ + j] = acc[j];
    bc[g] = acc[8] + enc_bih[g];
  }
}

// bf16 MFMA GEMM: C[M,N] = (A[M,K] @ B[N,K]^T (+bias)) * scale. 128x128, BK=32.
template <typename CT>
__global__ __launch_bounds__(256) void gemm_bf16(
    const short* __restrict__ A, long lda,
    const short* __restrict__ Bw, long ldb,
    const float* __restrict__ bias,
    CT* __restrict__ C, long ldc, int K, float scale)
{
  __shared__ short As[128 * 32];
  __shared__ short Bs[128 * 32];
  const int tid = threadIdx.x;
  const long row0 = (long)blockIdx.y * 128;
  const long col0 = (long)blockIdx.x * 128;
  const int wave = tid >> 6, lane = tid & 63;
  const int wm = (wave & 1) * 64, wn = (wave >> 1) * 64;
  const int r16 = lane & 15, quad = lane >> 4;
  f4v acc[4][4] = {};

  for (int k0 = 0; k0 < K; k0 += 32) {
#pragma unroll
    for (int r = 0; r < 2; ++r) {
      int idx = r * 256 + tid;
      int m = idx >> 2;
      int k8 = (idx & 3) * 8;
      __builtin_amdgcn_global_load_lds(
          (const __attribute__((address_space(1))) void*)(A + (row0 + m) * lda + k0 + k8),
          (__attribute__((address_space(3))) void*)(As + idx * 8), 16, 0, 0);
      __builtin_amdgcn_global_load_lds(
          (const __attribute__((address_space(1))) void*)(Bw + (col0 + m) * ldb + k0 + k8),
          (__attribute__((address_space(3))) void*)(Bs + idx * 8), 16, 0, 0);
    }
    __syncthreads();
    s8v af[4], bf[4];
#pragma unroll
    for (int i = 0; i < 4; ++i)
      af[i] = *(const s8v*)&As[(wm + i * 16 + r16) * 32 + quad * 8];
#pragma unroll
    for (int j = 0; j < 4; ++j)
      bf[j] = *(const s8v*)&Bs[(wn + j * 16 + r16) * 32 + quad * 8];
#pragma unroll
    for (int i = 0; i < 4; ++i)
#pragma unroll
      for (int j = 0; j < 4; ++j)
        acc[i][j] = __builtin_amdgcn_mfma_f32_16x16x32_bf16(af[i], bf[j], acc[i][j], 0, 0, 0);
    __syncthreads();
  }

#pragma unroll
  for (int i = 0; i < 4; ++i) {
    long rbase = row0 + wm + i * 16 + quad * 4;
#pragma unroll
    for (int j = 0; j < 4; ++j) {
      long c = col0 + wn + j * 16 + r16;
      float bv = bias ? bias[c] : 0.f;
#pragma unroll
      for (int rg = 0; rg < 4; ++rg)
        stc(&C[(rbase + rg) * ldc + c], (acc[i][j][rg] + bv) * scale);
    }
  }
}

// ---- Persistent GRU chain: enc 10 steps + dec 10 steps in ONE dispatch.
// Grid 256 blocks x 512 thr (8 waves). Block tile: 128 rows x 64 cols x 3g.
// LDS (dynamic 80KB): A dbuf 2x[128][64] bf16 (32KB) + B dbuf 2x[192][64]
// (48KB). BK=64, counted vmcnt(5), XOR-swizzled chunks, setprio.
// h fp32 persists in registers (16/thread); dec xg in regs (48/thread).
// Inter-step sync: 8-block row-panel barrier (atomic counter + threadfence).
__global__ __launch_bounds__(512, 2) void gru_chain(
    const short* __restrict__ whh_e, const float* __restrict__ bhh_e,
    const short* __restrict__ whh_d, const float* __restrict__ bhh_d,
    const short* __restrict__ xgb,   // (B,3H) bf16
    const float* __restrict__ items, // (B,L,IN)
    const float* __restrict__ Wc, const float* __restrict__ bc,
    short* __restrict__ enc_hist,    // (11,B,H) bf16
    short* __restrict__ dec_hist,    // (10,B,H) bf16
    unsigned* __restrict__ bar)      // 32 counters, pre-zeroed
{
  extern __shared__ short smem[];
  short* AsB = smem;            // 2 * 8192 shorts
  short* BsB = smem + 16384;    // 2 * 12288 shorts
  const int tid = threadIdx.x;
  const int f = blockIdx.x;
  // XCD-grouped remap: all 8 col-blocks of a row-panel on one XCD (heuristic).
  const int by = (f & 7) * 4 + (f >> 6);   // 0..31
  const int bx = (f >> 3) & 7;             // 0..7
  const long row0 = (long)by * 128;
  const int col0 = bx * 64;
  const int wave = tid >> 6, lane = tid & 63;
  const int rw = wave & 1, cw = wave >> 1;
  const int r16 = lane & 15, quad = lane >> 4;
  const int sw = r16 & 7;
  const int col = col0 + cw * 16 + r16;

  float hreg[16] = {};     // persistent fp32 h (rows rw*64+i*16+quad*4+rg, col)
  f4v acc[3][4];

  auto stage = [&](const short* Ap, const short* Whh, int buf, int k0) {
#pragma unroll
    for (int r = 0; r < 2; ++r) {            // A: 128x64 = 1024 chunks
      int idx = r * 512 + tid;
      int m = idx >> 3, c8 = idx & 7;
      int src = c8 ^ (m & 7);
      __builtin_amdgcn_global_load_lds(
          (const __attribute__((address_space(1))) void*)(Ap + (row0 + m) * H_ + k0 + src * 8),
          (__attribute__((address_space(3))) void*)(AsB + buf * 8192 + idx * 8), 16, 0, 0);
    }
#pragma unroll
    for (int r = 0; r < 3; ++r) {            // B: 192x64 = 1536 chunks
      int idx = r * 512 + tid;
      int m = idx >> 3, c8 = idx & 7;
      int src = c8 ^ (m & 7);
      int g = m >> 6, cc = m & 63;
      __builtin_amdgcn_global_load_lds(
          (const __attribute__((address_space(1))) void*)(Whh + ((long)g * H_ + col0 + cc) * H_ + k0 + src * 8),
          (__attribute__((address_space(3))) void*)(BsB + buf * 12288 + idx * 8), 16, 0, 0);
    }
  };

  auto kloop = [&](const short* Ap, const short* Whh) {
#pragma unroll
    for (int g = 0; g < 3; ++g)
#pragma unroll
      for (int i = 0; i < 4; ++i) acc[g][i] = (f4v){0.f, 0.f, 0.f, 0.f};
    stage(Ap, Whh, 0, 0);
    for (int k = 0; k < 8; ++k) {
      if (k < 7) {
        stage(Ap, Whh, (k + 1) & 1, (k + 1) * 64);
        asm volatile("s_waitcnt vmcnt(5)" ::: "memory");  // cur's 5 loads done
      } else {
        asm volatile("s_waitcnt vmcnt(0)" ::: "memory");
      }
      __builtin_amdgcn_s_barrier();
      const short* Asc = AsB + (k & 1) * 8192;
      const short* Bsc = BsB + (k & 1) * 12288;
      s8v af[4][2], bf[3][2];
#pragma unroll
      for (int i = 0; i < 4; ++i)
#pragma unroll
        for (int hh = 0; hh < 2; ++hh)
          af[i][hh] = *(const s8v*)&Asc[(rw * 64 + i * 16 + r16) * 64 + ((hh * 4 + quad) ^ sw) * 8];
#pragma unroll
      for (int g = 0; g < 3; ++g)
#pragma unroll
        for (int hh = 0; hh < 2; ++hh)
          bf[g][hh] = *(const s8v*)&Bsc[(g * 64 + cw * 16 + r16) * 64 + ((hh * 4 + quad) ^ sw) * 8];
      __builtin_amdgcn_s_setprio(1);
#pragma unroll
      for (int hh = 0; hh < 2; ++hh)
#pragma unroll
        for (int g = 0; g < 3; ++g)
#pragma unroll
          for (int i = 0; i < 4; ++i)
            acc[g][i] = __builtin_amdgcn_mfma_f32_16x16x32_bf16(af[i][hh], bf[g][hh], acc[g][i], 0, 0, 0);
      __builtin_amdgcn_s_setprio(0);
      __builtin_amdgcn_s_barrier();
    }
  };

  unsigned step = 0;
  auto gsync = [&]() {
    ++step;
    __syncthreads();   // all threads' hout stores drained to L2
    if (tid == 0) {
      __threadfence(); // release: writeback L2
      __hip_atomic_fetch_add(&bar[by], 1u, __ATOMIC_RELEASE, __HIP_MEMORY_SCOPE_AGENT);
      unsigned tgt = 8u * step;
      while (__hip_atomic_load(&bar[by], __ATOMIC_ACQUIRE, __HIP_MEMORY_SCOPE_AGENT) < tgt)
        __builtin_amdgcn_s_sleep(2);
      __threadfence(); // acquire: invalidate
    }
    __syncthreads();
  };

  // ---- Encoder phase ----
  float wc[3][8], bcv[3];
#pragma unroll
  for (int g = 0; g < 3; ++g) {
    const float* wr = Wc + ((long)g * H_ + col) * IN_;
#pragma unroll
    for (int j = 0; j < 8; ++j) wc[g][j] = wr[j];
    bcv[g] = bc[g * H_ + col];
  }
  {
    float bhr = bhh_e[col], bhz = bhh_e[col + H_], bhn = bhh_e[col + 2 * H_];
    for (int t = 0; t < L_; ++t) {
      kloop(enc_hist + (size_t)t * B_ * H_, whh_e);
      // stage items rows into LDS (reuse A buf0): 128 rows x 8 fp32
      float* itemS = (float*)AsB;
      const float* items_t = items + (size_t)t * IN_;
      {
        int i2 = tid * 2;
        int m = i2 >> 3, j = i2 & 7;
        itemS[i2] = items_t[(row0 + m) * (L_ * IN_) + j];
        itemS[i2 + 1] = items_t[(row0 + m) * (L_ * IN_) + j + 1];
      }
      __syncthreads();
      short* hout = enc_hist + (size_t)(t + 1) * B_ * H_;
#pragma unroll
      for (int i = 0; i < 4; ++i) {
#pragma unroll
        for (int rg = 0; rg < 4; ++rg) {
          int rl = rw * 64 + i * 16 + quad * 4 + rg;
          long row = row0 + rl;
          const float* it = itemS + rl * 8;
          float xr = bcv[0], xz = bcv[1], xn = bcv[2];
#pragma unroll
          for (int j = 0; j < 8; ++j) {
            float iv = it[j];
            xr += iv * wc[0][j];
            xz += iv * wc[1][j];
            xn += iv * wc[2][j];
          }
          float r = sig_fast(xr + acc[0][i][rg] + bhr);
          float z = sig_fast(xz + acc[1][i][rg] + bhz);
          float n = tanh_fast(xn + r * (acc[2][i][rg] + bhn));
          int hx = i * 4 + rg;
          float hv = (1.f - z) * n + z * hreg[hx];
          hreg[hx] = hv;
          hout[row * H_ + col] = f2bf(hv);
        }
      }
      gsync();
    }
  }

  // ---- Decoder phase: xg is t-invariant -> load once into registers ----
  float xv[3][16];
#pragma unroll
  for (int i = 0; i < 4; ++i)
#pragma unroll
    for (int rg = 0; rg < 4; ++rg) {
      long row = row0 + rw * 64 + i * 16 + quad * 4 + rg;
#pragma unroll
      for (int g = 0; g < 3; ++g)
        xv[g][i * 4 + rg] = bf2f(xgb[row * H3_ + g * H_ + col]);
    }
  {
    float bhr = bhh_d[col], bhz = bhh_d[col + H_], bhn = bhh_d[col + 2 * H_];
    for (int t = 0; t < L_; ++t) {
      const short* Ap = (t == 0) ? enc_hist + (size_t)10 * B_ * H_
                                 : dec_hist + (size_t)(t - 1) * B_ * H_;
      kloop(Ap, whh_d);
      short* hout = dec_hist + (size_t)t * B_ * H_;
#pragma unroll
      for (int i = 0; i < 4; ++i) {
#pragma unroll
        for (int rg = 0; rg < 4; ++rg) {
          int hx = i * 4 + rg;
          long row = row0 + rw * 64 + i * 16 + quad * 4 + rg;
          float r = sig_fast(xv[0][hx] + acc[0][i][rg] + bhr);
          float z = sig_fast(xv[1][hx] + acc[1][i][rg] + bhz);
          float n = tanh_fast(xv[2][hx] + r * (acc[2][i][rg] + bhn));
          float hv = (1.f - z) * n + z * hreg[hx];
          hreg[hx] = hv;
          hout[row * H_ + col] = f2bf(hv);
        }
      }
      if (t < L_ - 1) gsync();
    }
  }
}

// ---- batched out_seq: one block per b. ew3/a4 arrive pre-scaled by LOG2E2,
// staged as f32 in LDS with conflict-free contiguous-quarter access:
// lane reads f4v at j=lane*4 and j=256+lane*4 (16B lane stride).
// tanh(x) = 1 - 2*rcp(exp2(x*LOG2E2)+1); "1" folded into svtot=sum(v2).
__global__ __launch_bounds__(256) void out_seq_all(
    const short* __restrict__ ew3,   // (Lenc, B, W) bf16, prescaled
    const short* __restrict__ a4,    // (Ldec, B, W) bf16, prescaled
    const float* __restrict__ v2,
    float* __restrict__ out)
{
  __shared__ float se[L_ * W_];   // 20 KB
  __shared__ float sa[L_ * W_];   // 20 KB
  const int b = blockIdx.x;
  const int tid = threadIdx.x;
  for (int i = tid; i < L_ * 128; i += 256) {
    int row = i >> 7, q = i & 127;
    s4v ev = *(const s4v*)(ew3 + ((long)row * B_ + b) * W_ + q * 4);
    s4v av = *(const s4v*)(a4 + ((long)row * B_ + b) * W_ + q * 4);
    f4v e, a;
#pragma unroll
    for (int j = 0; j < 4; ++j) { e[j] = bf2f(ev[j]); a[j] = bf2f(av[j]); }
    *(f4v*)(se + row * W_ + q * 4) = e;   // 16B lane stride: conflict-free
    *(f4v*)(sa + row * W_ + q * 4) = a;
  }
  const int wave = tid >> 6, lane = tid & 63;
  float sv0[4], sv1[4], svtot = 0.f;
#pragma unroll
  for (int q = 0; q < 4; ++q) {
    float v = v2[lane * 4 + q];
    sv0[q] = -2.f * v; svtot += v;
    v = v2[256 + lane * 4 + q];
    sv1[q] = -2.f * v; svtot += v;
  }
#pragma unroll
  for (int off = 32; off; off >>= 1) svtot += __shfl_down(svtot, off, 64);
  svtot = __shfl(svtot, 0, 64);
  __syncthreads();

  int tprev = -1;
  f4v a0, a1;
#pragma unroll
  for (int pp = 0; pp < 25; ++pp) {
    int p = wave * 25 + pp;       // 100 (t,l) pairs over 4 waves
    int t = p / L_, l = p - t * L_;
    if (t != tprev) {             // wave-uniform branch; a-regs reused
      a0 = *(const f4v*)(sa + t * W_ + lane * 4);
      a1 = *(const f4v*)(sa + t * W_ + 256 + lane * 4);
      tprev = t;
    }
    f4v e0 = *(const f4v*)(se + l * W_ + lane * 4);
    f4v e1 = *(const f4v*)(se + l * W_ + 256 + lane * 4);
    float acc = 0.f;
#pragma unroll
    for (int q = 0; q < 4; ++q) {
      float x0 = __builtin_amdgcn_exp2f(e0[q] + a0[q]);
      acc += sv0[q] * __builtin_amdgcn_rcpf(x0 + 1.f);
      float x1 = __builtin_amdgcn_exp2f(e1[q] + a1[q]);
      acc += sv1[q] * __builtin_amdgcn_rcpf(x1 + 1.f);
    }
#pragma unroll
    for (int off = 32; off; off >>= 1) acc += __shfl_down(acc, off, 64);
    if (lane == 0) out[((long)b * L_ + t) * L_ + l] = svtot + acc;
  }
}

// ---- batched out_ori: one wave per (b,t). ----
__global__ __launch_bounds__(256) void out_ori_all(
    const short* __restrict__ dh,    // (Ldec, B, H) bf16
    const float* __restrict__ wori, const float* __restrict__ bori,
    float* __restrict__ out)
{
  int wid = (blockIdx.x * 256 + threadIdx.x) >> 6;   // b*L + t
  int lane = threadIdx.x & 63;
  int b = wid / L_, t = wid - b * L_;
  s8v hv = *(const s8v*)(dh + ((long)t * B_ + b) * H_ + lane * 8);
  float hf[8];
#pragma unroll
  for (int j = 0; j < 8; ++j) hf[j] = bf2f(hv[j]);
  float res[6];
#pragma unroll
  for (int o = 0; o < 6; ++o) {
    const float* wr = wori + (long)o * H3_ + H_ + lane * 8;
    float acc = 0.f;
#pragma unroll
    for (int j = 0; j < 8; ++j) acc += hf[j] * wr[j];
#pragma unroll
    for (int off = 32; off; off >>= 1) acc += __shfl_down(acc, off, 64);
    res[o] = acc;
  }
  if (lane == 0) {
    float* po = out + ORI_BASE + ((long)b * L_ + t) * 6;
#pragma unroll
    for (int o = 0; o < 6; ++o) po[o] = res[o] + bori[o];
  }
}

extern "C" void kernel_launch(void* const* d_in, const int* in_sizes, int n_in,
                              void* d_out, int out_size, void* d_ws, size_t ws_size,
                              hipStream_t stream)
{
  const float* items   = (const float*)d_in[0];
  const float* dec_in  = (const float*)d_in[1];
  const float* emb_w   = (const float*)d_in[2];
  const float* emb_b   = (const float*)d_in[3];
  const float* enc_wih = (const float*)d_in[4];
  const float* enc_whh = (const float*)d_in[5];
  const float* enc_bih = (const float*)d_in[6];
  const float* enc_bhh = (const float*)d_in[7];
  const float* dec_wih = (const float*)d_in[8];
  const float* dec_whh = (const float*)d_in[9];
  const float* dec_bih = (const float*)d_in[10];
  const float* dec_bhh = (const float*)d_in[11];
  const float* w3      = (const float*)d_in[14];
  const float* w4      = (const float*)d_in[15];
  const float* v2      = (const float*)d_in[20];
  const float* wori    = (const float*)d_in[23];
  const float* bori    = (const float*)d_in[24];
  float* out = (float*)d_out;

  char* ws = (char*)d_ws;
  size_t off = 0;
  auto alloc = [&](size_t bytes) { size_t o = off; off += (bytes + 255) & ~255UL; return o; };
  float* Wc       = (float*)(ws + alloc(H3_ * IN_ * 4));
  float* bc       = (float*)(ws + alloc(H3_ * 4));
  unsigned* bar   = (unsigned*)(ws + alloc(32 * 4));
  short* xgb      = (short*)(ws + alloc((size_t)B_ * H3_ * 2));          // 12 MiB
  short* enc_hist = (short*)(ws + alloc((size_t)11 * B_ * H_ * 2));      // 44 MiB
  short* dec_hist = (short*)(ws + alloc((size_t)L_ * B_ * H_ * 2));      // 40 MiB
  short* ew3      = (short*)(ws + alloc((size_t)L_ * B_ * W_ * 2));      // 40 MiB
  short* a4       = (short*)(ws + alloc((size_t)L_ * B_ * W_ * 2));      // 40 MiB
  short* whh_e    = (short*)(ws + alloc((size_t)H3_ * H_ * 2));
  short* whh_d    = (short*)(ws + alloc((size_t)H3_ * H_ * 2));
  short* wih_d    = (short*)(ws + alloc((size_t)H3_ * H_ * 2));
  short* w3b      = (short*)(ws + alloc((size_t)W_ * H_ * 2));
  short* w4b      = (short*)(ws + alloc((size_t)W_ * H_ * 2));
  short* decb     = (short*)(ws + alloc((size_t)B_ * H_ * 2));           // 4 MiB

  // ---- prep ----
  f2bf_k<<<(H3_ * H_ + 255) / 256, 256, 0, stream>>>(enc_whh, whh_e, H3_ * H_);
  f2bf_k<<<(H3_ * H_ + 255) / 256, 256, 0, stream>>>(dec_whh, whh_d, H3_ * H_);
  f2bf_k<<<(H3_ * H_ + 255) / 256, 256, 0, stream>>>(dec_wih, wih_d, H3_ * H_);
  f2bf_k<<<(W_ * H_ + 255) / 256, 256, 0, stream>>>(w3, w3b, W_ * H_);
  f2bf_k<<<(W_ * H_ + 255) / 256, 256, 0, stream>>>(w4, w4b, W_ * H_);
  f2bf_k<<<(B_ * H_ + 255) / 256, 256, 0, stream>>>(dec_in, decb, B_ * H_);
  build_wc<<<384, 256, 0, stream>>>(enc_wih, emb_w, emb_b, enc_bih, Wc, bc);

  hipMemsetAsync(enc_hist, 0, (size_t)B_ * H_ * 2, stream);      // slice 0 = 0
  hipMemsetAsync(bar, 0, 32 * 4, stream);                        // barrier ctrs

  // xg_dec = dec_in @ dec_wih^T + dec_bih (fixed across decoder steps), bf16
  gemm_bf16<short><<<dim3(12, 32), 256, 0, stream>>>(
      decb, H_, wih_d, H_, dec_bih, xgb, H3_, H_, 1.f);

  // ---- Persistent GRU chain: all 20 steps, one dispatch ----
  static bool attr_set = false;
  if (!attr_set) {
    (void)hipFuncSetAttribute((const void*)gru_chain,
                              hipFuncAttributeMaxDynamicSharedMemorySize, 81920);
    attr_set = true;
  }
  gru_chain<<<256, 512, 81920, stream>>>(
      whh_e, enc_bhh, whh_d, dec_bhh, xgb, items, Wc, bc,
      enc_hist, dec_hist, bar);

  // ---- Batched epilogue (ew3/a4 prescaled by LOG2E2 for out_seq) ----
  gemm_bf16<short><<<dim3(4, 320), 256, 0, stream>>>(
      enc_hist + (size_t)B_ * H_, H_, w3b, H_, nullptr, ew3, W_, H_, LOG2E2);
  gemm_bf16<short><<<dim3(4, 320), 256, 0, stream>>>(
      dec_hist, H_, w4b, H_, nullptr, a4, W_, H_, LOG2E2);
  out_seq_all<<<B_, 256, 0, stream>>>(ew3, a4, v2, out);
  out_ori_all<<<(B_ * L_) / 4, 256, 0, stream>>>(dec_hist, wori, bori, out);
}

// Round 4
// 931.488 us; speedup vs baseline: 1.1043x; 1.1043x over previous
//
#include <hip/hip_runtime.h>
#include <hip/hip_bf16.h>

// PointerNetwork: B=4096, L=10, IN=8, H=512, W=512. fp32 in/out, ws=256MiB.
// log_softmax over size-1 axes => hi==he==0. Surviving compute:
//   enc GRU, ew3 = h_enc @ w3^T, dec GRU, a4 = h_dec @ w4^T,
//   out_seq = tanh(ew3+a4)@v2, out_ori = h_dec @ wori[:,H:2H]^T + bori.
// Round 10 (= Round 9 + 2 correctness fixes): block-private persistent GRU
// chain. 128 blocks x 512 thr; each block owns 32 rows x ALL 512 cols -> h
// never leaves the block (LDS/regs), zero inter-block sync. Weights streamed
// per step (L2-resident). K augmented to 544: [512 h | 8 items | 1.0 | pad],
// biases folded into col 520; n-gate xn via 4th sparse gate (rows 1536..2047).
// FIX 1: A cols 0..511 (h0) zeroed in prologue (was stale LDS -> NaN).
// FIX 2: n-gate rows of We no longer carry Wc items-columns (was
// double-counting items inside the r-gated term).

#define B_   4096
#define L_   10
#define IN_  8
#define H_   512
#define H3_  1536
#define W_   512
#define KAUG 544
#define ORI_BASE (B_ * L_ * L_)   // 409600

typedef __attribute__((ext_vector_type(8))) short s8v;
typedef __attribute__((ext_vector_type(4))) short s4v;
typedef __attribute__((ext_vector_type(4))) float f4v;

#define LOG2E  1.4426950408889634f
#define LOG2E2 2.8853900817779268f

__device__ __forceinline__ float sig_fast(float x) {
  float e = __builtin_amdgcn_exp2f(-x * LOG2E);
  return __builtin_amdgcn_rcpf(1.f + e);
}
__device__ __forceinline__ float tanh_fast(float x) {
  float e = __builtin_amdgcn_exp2f(x * LOG2E2);
  return 1.f - 2.f * __builtin_amdgcn_rcpf(e + 1.f);
}
__device__ __forceinline__ short f2bf(float f) {
  __hip_bfloat16 h = __float2bfloat16(f);
  return __builtin_bit_cast(short, h);
}
__device__ __forceinline__ float bf2f(short s) {
  __hip_bfloat16 h = __builtin_bit_cast(__hip_bfloat16, s);
  return __bfloat162float(h);
}
__device__ __forceinline__ void stc(float* p, float v) { *p = v; }
__device__ __forceinline__ void stc(short* p, float v) { *p = f2bf(v); }

__global__ __launch_bounds__(256) void f2bf_k(const float* __restrict__ src,
                                              short* __restrict__ dst, int n)
{
  int i = blockIdx.x * 256 + threadIdx.x;
  if (i < n) dst[i] = f2bf(src[i]);
}

// Fold embedding into encoder input weight. One wave per g-row (1536 waves).
__global__ __launch_bounds__(256) void build_wc(
    const float* __restrict__ enc_wih, const float* __restrict__ emb_w,
    const float* __restrict__ emb_b, const float* __restrict__ enc_bih,
    float* __restrict__ Wc, float* __restrict__ bc)
{
  __shared__ float se[H_ * IN_];   // 16 KB
  __shared__ float sb[H_];         // 2 KB
  const int tid = threadIdx.x;
  for (int i = tid; i < H_ * IN_; i += 256) se[i] = emb_w[i];
  for (int i = tid; i < H_; i += 256) sb[i] = emb_b[i];
  __syncthreads();
  int g = (blockIdx.x * 256 + tid) >> 6;
  int lane = tid & 63;
  const float* wr = enc_wih + (long)g * H_ + lane * 8;
  float w8[8];
#pragma unroll
  for (int j = 0; j < 8; ++j) w8[j] = wr[j];
  float acc[9] = {};
#pragma unroll
  for (int kk = 0; kk < 8; ++kk) {
    int k = lane * 8 + kk;
#pragma unroll
    for (int j = 0; j < 8; ++j) acc[j] += w8[kk] * se[k * IN_ + j];
    acc[8] += w8[kk] * sb[k];
  }
#pragma unroll
  for (int j = 0; j < 9; ++j)
#pragma unroll
    for (int off = 32; off; off >>= 1) acc[j] += __shfl_down(acc[j], off, 64);
  if (lane == 0) {
#pragma unroll
    for (int j = 0; j < 8; ++j) Wc[g * IN_ + j] = acc[j];
    bc[g] = acc[8] + enc_bih[g];
  }
}

// Build augmented weights:
// We [2048][544]: rows 0..1023 (r,z): [0:512]=whh_e, [512:520]=Wc,
//   [520]=bc+bhh, rest 0. rows 1024..1535 (n): [0:512]=whh_e, [512:520]=0,
//   [520]=bhh (items part lives in the xn gate). rows 1536..2047 (xn):
//   [512:520]=Wc_n, [520]=bc_n, rest 0.
// Wd [1536][544]: [0:512]=whh_d, [520]=bhh_d, rest 0.
__global__ __launch_bounds__(256) void build_waug(
    const float* __restrict__ whh_e, const float* __restrict__ bhh_e,
    const float* __restrict__ whh_d, const float* __restrict__ bhh_d,
    const float* __restrict__ Wc, const float* __restrict__ bc,
    short* __restrict__ We, short* __restrict__ Wd)
{
  long i = (long)blockIdx.x * 256 + threadIdx.x;
  if (i >= 2048L * KAUG) return;
  int r = (int)(i / KAUG), c = (int)(i - (long)r * KAUG);
  float ve;
  if (r < 1536) {
    if (c < 512) ve = whh_e[(long)r * 512 + c];
    else if (c < 520) ve = (r < 1024) ? Wc[(long)r * 8 + (c - 512)] : 0.f;
    else if (c == 520) ve = (r < 1024) ? (bc[r] + bhh_e[r]) : bhh_e[r];
    else ve = 0.f;
  } else {
    int rr = r - 1536 + 1024;   // n-gate row in Wc/bc space
    if (c >= 512 && c < 520) ve = Wc[(long)rr * 8 + (c - 512)];
    else if (c == 520) ve = bc[rr];
    else ve = 0.f;
  }
  We[i] = f2bf(ve);
  if (r < 1536) {
    float vd;
    if (c < 512) vd = whh_d[(long)r * 512 + c];
    else if (c == 520) vd = bhh_d[r];
    else vd = 0.f;
    Wd[(long)r * KAUG + c] = f2bf(vd);
  }
}

// bf16 MFMA GEMM: C[M,N] = (A[M,K] @ B[N,K]^T (+bias)) * scale. 128x128, BK=32.
template <typename CT>
__global__ __launch_bounds__(256) void gemm_bf16(
    const short* __restrict__ A, long lda,
    const short* __restrict__ Bw, long ldb,
    const float* __restrict__ bias,
    CT* __restrict__ C, long ldc, int K, float scale)
{
  __shared__ short As[128 * 32];
  __shared__ short Bs[128 * 32];
  const int tid = threadIdx.x;
  const long row0 = (long)blockIdx.y * 128;
  const long col0 = (long)blockIdx.x * 128;
  const int wave = tid >> 6, lane = tid & 63;
  const int wm = (wave & 1) * 64, wn = (wave >> 1) * 64;
  const int r16 = lane & 15, quad = lane >> 4;
  f4v acc[4][4] = {};

  for (int k0 = 0; k0 < K; k0 += 32) {
#pragma unroll
    for (int r = 0; r < 2; ++r) {
      int idx = r * 256 + tid;
      int m = idx >> 2;
      int k8 = (idx & 3) * 8;
      __builtin_amdgcn_global_load_lds(
          (const __attribute__((address_space(1))) void*)(A + (row0 + m) * lda + k0 + k8),
          (__attribute__((address_space(3))) void*)(As + idx * 8), 16, 0, 0);
      __builtin_amdgcn_global_load_lds(
          (const __attribute__((address_space(1))) void*)(Bw + (col0 + m) * ldb + k0 + k8),
          (__attribute__((address_space(3))) void*)(Bs + idx * 8), 16, 0, 0);
    }
    __syncthreads();
    s8v af[4], bf[4];
#pragma unroll
    for (int i = 0; i < 4; ++i)
      af[i] = *(const s8v*)&As[(wm + i * 16 + r16) * 32 + quad * 8];
#pragma unroll
    for (int j = 0; j < 4; ++j)
      bf[j] = *(const s8v*)&Bs[(wn + j * 16 + r16) * 32 + quad * 8];
#pragma unroll
    for (int i = 0; i < 4; ++i)
#pragma unroll
      for (int j = 0; j < 4; ++j)
        acc[i][j] = __builtin_amdgcn_mfma_f32_16x16x32_bf16(af[i], bf[j], acc[i][j], 0, 0, 0);
    __syncthreads();
  }

#pragma unroll
  for (int i = 0; i < 4; ++i) {
    long rbase = row0 + wm + i * 16 + quad * 4;
#pragma unroll
    for (int j = 0; j < 4; ++j) {
      long c = col0 + wn + j * 16 + r16;
      float bv = bias ? bias[c] : 0.f;
#pragma unroll
      for (int rg = 0; rg < 4; ++rg)
        stc(&C[(rbase + rg) * ldc + c], (acc[i][j][rg] + bv) * scale);
    }
  }
}

// ---- Block-private persistent GRU chain ----
// 128 blocks x 512 thr (8 waves). Block: rows [bid*32, +32), all 512 cols.
// LDS: A [32][544] bf16 (34.8KB) operand+state; Bt 3 x [512][32] (96KB)
// weight chunk triple-buffer. Wave wv owns output cols [wv*64, +64).
// Chunks per step: (k0i 0..16) x (g 0..2) + enc-only xn chunk (g=3,k0i=16).
__global__ __launch_bounds__(512, 2) void gru_chain(
    const short* __restrict__ We,    // [2048][544] bf16
    const short* __restrict__ Wd,    // [1536][544] bf16
    const short* __restrict__ xgb,   // (B,3H) bf16
    const float* __restrict__ items, // (B,L,IN) fp32
    short* __restrict__ enc_hist,    // (10,B,H) bf16
    short* __restrict__ dec_hist)    // (10,B,H) bf16
{
  extern __shared__ short smem[];
  short* A  = smem;            // 32*544 = 17408 shorts
  short* Bt = smem + 17408;    // 3 * 16384 shorts
  const int tid = threadIdx.x;
  const int wv = tid >> 6, lane = tid & 63;
  const int r16 = lane & 15, quad = lane >> 4;
  const long row0 = (long)blockIdx.x * 32;

  // stage chunk (g, k0i) into buf: [512 rows][32 k] dense, row-major 64B pitch.
  // Per wave-load: 16 rows x 4 k-chunks; lane = rloc*4 + c8 matches the HW
  // linear LDS dest (base + lane*16B) exactly.
  auto stage = [&](const short* W, int g, int k0i, int buf) {
    const short* srcb = W + ((long)(g * 512 + wv * 64) * KAUG + k0i * 32);
    short* dstb = Bt + buf * 16384 + (wv * 64) * 32;
#pragma unroll
    for (int l = 0; l < 4; ++l) {
      int rloc = l * 16 + (lane >> 2);
      int c8 = lane & 3;
      __builtin_amdgcn_global_load_lds(
          (const __attribute__((address_space(1))) void*)(srcb + (long)rloc * KAUG + c8 * 8),
          (__attribute__((address_space(3))) void*)(dstb + l * 512 + lane * 8), 16, 0, 0);
    }
  };

  // ---- prologue: zero ALL of A (h0 = 0!), then col 520 = 1.0, items t=0 ----
  for (int idx = tid; idx < 32 * KAUG / 8; idx += 512)
    *(s8v*)&A[idx * 8] = (s8v){0, 0, 0, 0, 0, 0, 0, 0};
  __syncthreads();
  if (tid < 32) A[tid * KAUG + 520] = (short)0x3F80;   // 1.0 bf16
  if (tid < 256) {
    int m = tid >> 3, j = tid & 7;
    A[m * KAUG + 512 + j] = f2bf(items[(row0 + m) * (L_ * IN_) + j]);
  }
  __syncthreads();

  float hc[2][4][4] = {};    // fp32 h carry, block-private
  int cc = 0;                // global chunk counter (buffer rotation)
  stage(We, 0, 0, 0);        // prefetch very first chunk

  for (int t = 0; t < 20; ++t) {
    const bool enc = (t < 10);
    const short* W = enc ? We : Wd;
    const int nch = enc ? 52 : 51;
    f4v acc[3][2][4] = {};
    f4v accx[2][4] = {};
    s8v af[2];

    for (int k0i = 0; k0i < 17; ++k0i) {
#pragma unroll
      for (int g = 0; g < 3; ++g) {
        const int c = k0i * 3 + g;
        if (c + 1 < 51) {
          stage(W, (g == 2) ? 0 : g + 1, (g == 2) ? k0i + 1 : k0i, (cc + c + 1) % 3);
          asm volatile("s_waitcnt vmcnt(4)" ::: "memory");
        } else if (enc) {                 // c == 50, stage xn chunk
          stage(W, 3, 16, (cc + 51) % 3);
          asm volatile("s_waitcnt vmcnt(4)" ::: "memory");
        } else {
          asm volatile("s_waitcnt vmcnt(0)" ::: "memory");
        }
        __builtin_amdgcn_s_barrier();
        const short* Bb = Bt + ((cc + c) % 3) * 16384;
        if (g == 0) {
          af[0] = *(const s8v*)&A[(r16) * KAUG + k0i * 32 + quad * 8];
          af[1] = *(const s8v*)&A[(16 + r16) * KAUG + k0i * 32 + quad * 8];
        }
        s8v bfr[4];
#pragma unroll
        for (int cf = 0; cf < 4; ++cf)
          bfr[cf] = *(const s8v*)&Bb[(wv * 64 + cf * 16 + r16) * 32 + quad * 8];
        __builtin_amdgcn_s_setprio(1);
#pragma unroll
        for (int rf = 0; rf < 2; ++rf)
#pragma unroll
          for (int cf = 0; cf < 4; ++cf)
            acc[g][rf][cf] = __builtin_amdgcn_mfma_f32_16x16x32_bf16(
                af[rf], bfr[cf], acc[g][rf][cf], 0, 0, 0);
        __builtin_amdgcn_s_setprio(0);
      }
    }
    if (enc) {   // xn chunk (g=3, k0i=16): af from k0i=16 still live
      asm volatile("s_waitcnt vmcnt(0)" ::: "memory");
      __builtin_amdgcn_s_barrier();
      const short* Bb = Bt + ((cc + 51) % 3) * 16384;
      s8v bfr[4];
#pragma unroll
      for (int cf = 0; cf < 4; ++cf)
        bfr[cf] = *(const s8v*)&Bb[(wv * 64 + cf * 16 + r16) * 32 + quad * 8];
      __builtin_amdgcn_s_setprio(1);
#pragma unroll
      for (int rf = 0; rf < 2; ++rf)
#pragma unroll
        for (int cf = 0; cf < 4; ++cf)
          accx[rf][cf] = __builtin_amdgcn_mfma_f32_16x16x32_bf16(
              af[rf], bfr[cf], accx[rf][cf], 0, 0, 0);
      __builtin_amdgcn_s_setprio(0);
    }
    cc += nch;

    // ---- epilogue: all waves past last chunk barrier; A reads retired ----
#pragma unroll
    for (int rf = 0; rf < 2; ++rf)
#pragma unroll
      for (int cf = 0; cf < 4; ++cf)
#pragma unroll
        for (int rg = 0; rg < 4; ++rg) {
          int row = rf * 16 + quad * 4 + rg;
          int col = wv * 64 + cf * 16 + r16;
          float xr = 0.f, xz = 0.f, xn;
          if (enc) {
            xn = accx[rf][cf][rg];
          } else {
            long gx = (row0 + row) * H3_ + col;
            xr = bf2f(xgb[gx]);
            xz = bf2f(xgb[gx + 512]);
            xn = bf2f(xgb[gx + 1024]);
          }
          float rr = sig_fast(xr + acc[0][rf][cf][rg]);
          float zz = sig_fast(xz + acc[1][rf][cf][rg]);
          float nn = tanh_fast(xn + rr * acc[2][rf][cf][rg]);
          float hv = (1.f - zz) * nn + zz * hc[rf][cf][rg];
          hc[rf][cf][rg] = hv;
          A[row * KAUG + col] = f2bf(hv);   // next step's operand
        }
    if (t + 1 < 10 && tid < 256) {          // items for next enc step
      int m = tid >> 3, j = tid & 7;
      A[m * KAUG + 512 + j] = f2bf(items[(row0 + m) * (L_ * IN_) + (t + 1) * IN_ + j]);
    }
    __syncthreads();   // h writes visible to all (drains lgkm + vm)

    // coalesced history write from A (cols < 512 only)
    short* hist = enc ? (enc_hist + (size_t)t * B_ * H_)
                      : (dec_hist + (size_t)(t - 10) * B_ * H_);
#pragma unroll
    for (int l = 0; l < 4; ++l) {
      int idx = l * 512 + tid;
      int row = idx >> 6, c8 = idx & 63;
      s8v v = *(const s8v*)&A[row * KAUG + c8 * 8];
      *(s8v*)&hist[(row0 + row) * H_ + c8 * 8] = v;
    }
    // prefetch next step's chunk0 (after syncthreads so it stays in flight)
    if (t < 19) {
      const short* Wn = (t + 1 < 10) ? We : Wd;
      stage(Wn, 0, 0, cc % 3);
    }
  }
}

// ---- batched out_seq: one block per b. ew3/a4 arrive pre-scaled by LOG2E2,
// staged as f32 in LDS with conflict-free contiguous-quarter access.
// tanh(x) = 1 - 2*rcp(exp2(x*LOG2E2)+1); "1" folded into svtot=sum(v2).
__global__ __launch_bounds__(256) void out_seq_all(
    const short* __restrict__ ew3,   // (Lenc, B, W) bf16, prescaled
    const short* __restrict__ a4,    // (Ldec, B, W) bf16, prescaled
    const float* __restrict__ v2,
    float* __restrict__ out)
{
  __shared__ float se[L_ * W_];   // 20 KB
  __shared__ float sa[L_ * W_];   // 20 KB
  const int b = blockIdx.x;
  const int tid = threadIdx.x;
  for (int i = tid; i < L_ * 128; i += 256) {
    int row = i >> 7, q = i & 127;
    s4v ev = *(const s4v*)(ew3 + ((long)row * B_ + b) * W_ + q * 4);
    s4v av = *(const s4v*)(a4 + ((long)row * B_ + b) * W_ + q * 4);
    f4v e, a;
#pragma unroll
    for (int j = 0; j < 4; ++j) { e[j] = bf2f(ev[j]); a[j] = bf2f(av[j]); }
    *(f4v*)(se + row * W_ + q * 4) = e;
    *(f4v*)(sa + row * W_ + q * 4) = a;
  }
  const int wave = tid >> 6, lane = tid & 63;
  float sv0[4], sv1[4], svtot = 0.f;
#pragma unroll
  for (int q = 0; q < 4; ++q) {
    float v = v2[lane * 4 + q];
    sv0[q] = -2.f * v; svtot += v;
    v = v2[256 + lane * 4 + q];
    sv1[q] = -2.f * v; svtot += v;
  }
#pragma unroll
  for (int off = 32; off; off >>= 1) svtot += __shfl_down(svtot, off, 64);
  svtot = __shfl(svtot, 0, 64);
  __syncthreads();

  int tprev = -1;
  f4v a0, a1;
#pragma unroll
  for (int pp = 0; pp < 25; ++pp) {
    int p = wave * 25 + pp;       // 100 (t,l) pairs over 4 waves
    int t = p / L_, l = p - t * L_;
    if (t != tprev) {
      a0 = *(const f4v*)(sa + t * W_ + lane * 4);
      a1 = *(const f4v*)(sa + t * W_ + 256 + lane * 4);
      tprev = t;
    }
    f4v e0 = *(const f4v*)(se + l * W_ + lane * 4);
    f4v e1 = *(const f4v*)(se + l * W_ + 256 + lane * 4);
    float acc = 0.f;
#pragma unroll
    for (int q = 0; q < 4; ++q) {
      float x0 = __builtin_amdgcn_exp2f(e0[q] + a0[q]);
      acc += sv0[q] * __builtin_amdgcn_rcpf(x0 + 1.f);
      float x1 = __builtin_amdgcn_exp2f(e1[q] + a1[q]);
      acc += sv1[q] * __builtin_amdgcn_rcpf(x1 + 1.f);
    }
#pragma unroll
    for (int off = 32; off; off >>= 1) acc += __shfl_down(acc, off, 64);
    if (lane == 0) out[((long)b * L_ + t) * L_ + l] = svtot + acc;
  }
}

// ---- batched out_ori: one wave per (b,t). ----
__global__ __launch_bounds__(256) void out_ori_all(
    const short* __restrict__ dh,    // (Ldec, B, H) bf16
    const float* __restrict__ wori, const float* __restrict__ bori,
    float* __restrict__ out)
{
  int wid = (blockIdx.x * 256 + threadIdx.x) >> 6;   // b*L + t
  int lane = threadIdx.x & 63;
  int b = wid / L_, t = wid - b * L_;
  s8v hv = *(const s8v*)(dh + ((long)t * B_ + b) * H_ + lane * 8);
  float hf[8];
#pragma unroll
  for (int j = 0; j < 8; ++j) hf[j] = bf2f(hv[j]);
  float res[6];
#pragma unroll
  for (int o = 0; o < 6; ++o) {
    const float* wr = wori + (long)o * H3_ + H_ + lane * 8;
    float acc = 0.f;
#pragma unroll
    for (int j = 0; j < 8; ++j) acc += hf[j] * wr[j];
#pragma unroll
    for (int off = 32; off; off >>= 1) acc += __shfl_down(acc, off, 64);
    res[o] = acc;
  }
  if (lane == 0) {
    float* po = out + ORI_BASE + ((long)b * L_ + t) * 6;
#pragma unroll
    for (int o = 0; o < 6; ++o) po[o] = res[o] + bori[o];
  }
}

extern "C" void kernel_launch(void* const* d_in, const int* in_sizes, int n_in,
                              void* d_out, int out_size, void* d_ws, size_t ws_size,
                              hipStream_t stream)
{
  const float* items   = (const float*)d_in[0];
  const float* dec_in  = (const float*)d_in[1];
  const float* emb_w   = (const float*)d_in[2];
  const float* emb_b   = (const float*)d_in[3];
  const float* enc_wih = (const float*)d_in[4];
  const float* enc_whh = (const float*)d_in[5];
  const float* enc_bih = (const float*)d_in[6];
  const float* enc_bhh = (const float*)d_in[7];
  const float* dec_wih = (const float*)d_in[8];
  const float* dec_whh = (const float*)d_in[9];
  const float* dec_bih = (const float*)d_in[10];
  const float* dec_bhh = (const float*)d_in[11];
  const float* w3      = (const float*)d_in[14];
  const float* w4      = (const float*)d_in[15];
  const float* v2      = (const float*)d_in[20];
  const float* wori    = (const float*)d_in[23];
  const float* bori    = (const float*)d_in[24];
  float* out = (float*)d_out;

  char* ws = (char*)d_ws;
  size_t off = 0;
  auto alloc = [&](size_t bytes) { size_t o = off; off += (bytes + 255) & ~255UL; return o; };
  float* Wc       = (float*)(ws + alloc(H3_ * IN_ * 4));
  float* bc       = (float*)(ws + alloc(H3_ * 4));
  short* We       = (short*)(ws + alloc((size_t)2048 * KAUG * 2));       // 2.2 MiB
  short* Wd       = (short*)(ws + alloc((size_t)H3_ * KAUG * 2));       // 1.7 MiB
  short* xgb      = (short*)(ws + alloc((size_t)B_ * H3_ * 2));          // 12 MiB
  short* enc_hist = (short*)(ws + alloc((size_t)L_ * B_ * H_ * 2));      // 40 MiB
  short* dec_hist = (short*)(ws + alloc((size_t)L_ * B_ * H_ * 2));      // 40 MiB
  short* ew3      = (short*)(ws + alloc((size_t)L_ * B_ * W_ * 2));      // 40 MiB
  short* a4       = (short*)(ws + alloc((size_t)L_ * B_ * W_ * 2));      // 40 MiB
  short* wih_d    = (short*)(ws + alloc((size_t)H3_ * H_ * 2));
  short* w3b      = (short*)(ws + alloc((size_t)W_ * H_ * 2));
  short* w4b      = (short*)(ws + alloc((size_t)W_ * H_ * 2));
  short* decb     = (short*)(ws + alloc((size_t)B_ * H_ * 2));           // 4 MiB

  // ---- prep ----
  f2bf_k<<<(H3_ * H_ + 255) / 256, 256, 0, stream>>>(dec_wih, wih_d, H3_ * H_);
  f2bf_k<<<(W_ * H_ + 255) / 256, 256, 0, stream>>>(w3, w3b, W_ * H_);
  f2bf_k<<<(W_ * H_ + 255) / 256, 256, 0, stream>>>(w4, w4b, W_ * H_);
  f2bf_k<<<(B_ * H_ + 255) / 256, 256, 0, stream>>>(dec_in, decb, B_ * H_);
  build_wc<<<384, 256, 0, stream>>>(enc_wih, emb_w, emb_b, enc_bih, Wc, bc);
  build_waug<<<(2048 * KAUG + 255) / 256, 256, 0, stream>>>(
      enc_whh, enc_bhh, dec_whh, dec_bhh, Wc, bc, We, Wd);

  // xg_dec = dec_in @ dec_wih^T + dec_bih (fixed across decoder steps), bf16
  gemm_bf16<short><<<dim3(12, 32), 256, 0, stream>>>(
      decb, H_, wih_d, H_, dec_bih, xgb, H3_, H_, 1.f);

  // ---- Persistent block-private GRU chain: all 20 steps, one dispatch ----
  static bool attr_set = false;
  if (!attr_set) {
    (void)hipFuncSetAttribute((const void*)gru_chain,
                              hipFuncAttributeMaxDynamicSharedMemorySize, 133120);
    attr_set = true;
  }
  gru_chain<<<128, 512, 133120, stream>>>(
      We, Wd, xgb, items, enc_hist, dec_hist);

  // ---- Batched epilogue (ew3/a4 prescaled by LOG2E2 for out_seq) ----
  gemm_bf16<short><<<dim3(4, 320), 256, 0, stream>>>(
      enc_hist, H_, w3b, H_, nullptr, ew3, W_, H_, LOG2E2);
  gemm_bf16<short><<<dim3(4, 320), 256, 0, stream>>>(
      dec_hist, H_, w4b, H_, nullptr, a4, W_, H_, LOG2E2);
  out_seq_all<<<B_, 256, 0, stream>>>(ew3, a4, v2, out);
  out_ori_all<<<(B_ * L_) / 4, 256, 0, stream>>>(dec_hist, wori, bori, out);
}

// Round 5
// 602.501 us; speedup vs baseline: 1.7072x; 1.5460x over previous
//
#include <hip/hip_runtime.h>
#include <hip/hip_bf16.h>

// PointerNetwork: B=4096, L=10, IN=8, H=512, W=512. fp32 in/out, ws=256MiB.
// log_softmax over size-1 axes => hi==he==0. Surviving compute:
//   enc GRU, ew3 = h_enc @ w3^T, dec GRU, a4 = h_dec @ w4^T,
//   out_seq = tanh(ew3+a4)@v2, out_ori = h_dec @ wori[:,H:2H]^T + bori.
// Round 11: revert recurrence to Round-1 per-step gru_fused (persistent
// variants measured worse: latency-bound at 1 blk/CU, L2 thrash). New:
// pipelined gemm_bf16 (128x128, BK=64 dbuf, counted vmcnt(8), swizzled LDS,
// setprio — the loop proven in gru_fused) for xg + ew3 + a4; out_seq_all
// conflict-free contiguous-quarter layout; prep f2bf fused into one kernel.

#define B_   4096
#define L_   10
#define IN_  8
#define H_   512
#define H3_  1536
#define W_   512
#define ORI_BASE (B_ * L_ * L_)   // 409600

typedef __attribute__((ext_vector_type(8))) short s8v;
typedef __attribute__((ext_vector_type(4))) short s4v;
typedef __attribute__((ext_vector_type(4))) float f4v;

#define LOG2E  1.4426950408889634f
#define LOG2E2 2.8853900817779268f

__device__ __forceinline__ float sig_fast(float x) {
  float e = __builtin_amdgcn_exp2f(-x * LOG2E);
  return __builtin_amdgcn_rcpf(1.f + e);
}
__device__ __forceinline__ float tanh_fast(float x) {
  float e = __builtin_amdgcn_exp2f(x * LOG2E2);
  return 1.f - 2.f * __builtin_amdgcn_rcpf(e + 1.f);
}
__device__ __forceinline__ short f2bf(float f) {
  __hip_bfloat16 h = __float2bfloat16(f);
  return __builtin_bit_cast(short, h);
}
__device__ __forceinline__ float bf2f(short s) {
  __hip_bfloat16 h = __builtin_bit_cast(__hip_bfloat16, s);
  return __bfloat162float(h);
}
__device__ __forceinline__ void stc(float* p, float v) { *p = v; }
__device__ __forceinline__ void stc(short* p, float v) { *p = f2bf(v); }

// ---- fused prep: all fp32->bf16 conversions in one dispatch (6 segments) ----
__global__ __launch_bounds__(256) void prep_all(
    const float* __restrict__ s0, short* __restrict__ d0,   // enc_whh 786432
    const float* __restrict__ s1, short* __restrict__ d1,   // dec_whh 786432
    const float* __restrict__ s2, short* __restrict__ d2,   // dec_wih 786432
    const float* __restrict__ s3, short* __restrict__ d3,   // w3      262144
    const float* __restrict__ s4, short* __restrict__ d4,   // w4      262144
    const float* __restrict__ s5, short* __restrict__ d5)   // dec_in  2097152
{
  long i8 = (long)blockIdx.x * 256 + threadIdx.x;   // unit = 8 elements
  const float* s; short* d; long off;
  if      (i8 < 98304)  { s = s0; d = d0; off = i8; }
  else if (i8 < 196608) { s = s1; d = d1; off = i8 - 98304; }
  else if (i8 < 294912) { s = s2; d = d2; off = i8 - 196608; }
  else if (i8 < 327680) { s = s3; d = d3; off = i8 - 294912; }
  else if (i8 < 360448) { s = s4; d = d4; off = i8 - 327680; }
  else if (i8 < 622592) { s = s5; d = d5; off = i8 - 360448; }
  else return;
  const float* sp = s + off * 8;
  s8v v;
#pragma unroll
  for (int j = 0; j < 8; ++j) v[j] = f2bf(sp[j]);
  *(s8v*)(d + off * 8) = v;
}

// Fold embedding into encoder input weight. One wave per g-row (1536 waves).
__global__ __launch_bounds__(256) void build_wc(
    const float* __restrict__ enc_wih, const float* __restrict__ emb_w,
    const float* __restrict__ emb_b, const float* __restrict__ enc_bih,
    float* __restrict__ Wc, float* __restrict__ bc)
{
  __shared__ float se[H_ * IN_];   // 16 KB
  __shared__ float sb[H_];         // 2 KB
  const int tid = threadIdx.x;
  for (int i = tid; i < H_ * IN_; i += 256) se[i] = emb_w[i];
  for (int i = tid; i < H_; i += 256) sb[i] = emb_b[i];
  __syncthreads();
  int g = (blockIdx.x * 256 + tid) >> 6;
  int lane = tid & 63;
  const float* wr = enc_wih + (long)g * H_ + lane * 8;
  float w8[8];
#pragma unroll
  for (int j = 0; j < 8; ++j) w8[j] = wr[j];
  float acc[9] = {};
#pragma unroll
  for (int kk = 0; kk < 8; ++kk) {
    int k = lane * 8 + kk;
#pragma unroll
    for (int j = 0; j < 8; ++j) acc[j] += w8[kk] * se[k * IN_ + j];
    acc[8] += w8[kk] * sb[k];
  }
#pragma unroll
  for (int j = 0; j < 9; ++j)
#pragma unroll
    for (int off = 32; off; off >>= 1) acc[j] += __shfl_down(acc[j], off, 64);
  if (lane == 0) {
#pragma unroll
    for (int j = 0; j < 8; ++j) Wc[g * IN_ + j] = acc[j];
    bc[g] = acc[8] + enc_bih[g];
  }
}

// ---- Pipelined bf16 MFMA GEMM: C[M,N] = (A@B^T (+bias))*scale.
// 128x128 tile, BK=64, double-buffered LDS (64KB, 2 blk/CU), counted
// vmcnt(8), XOR-swizzled 16B chunks (both-sides), setprio around MFMA.
template <typename CT>
__global__ __launch_bounds__(256) void gemm_bf16(
    const short* __restrict__ A, long lda,
    const short* __restrict__ Bw, long ldb,
    const float* __restrict__ bias,
    CT* __restrict__ C, long ldc, int K, float scale)
{
  __shared__ short As[2][128 * 64];   // 32 KB
  __shared__ short Bs[2][128 * 64];   // 32 KB
  const int tid = threadIdx.x;
  const long row0 = (long)blockIdx.y * 128;
  const long col0 = (long)blockIdx.x * 128;
  const int wave = tid >> 6, lane = tid & 63;
  const int wm = (wave & 1) * 64, wn = (wave >> 1) * 64;
  const int r16 = lane & 15, quad = lane >> 4;
  const int sw = r16 & 7;
  f4v acc[4][4] = {};

  auto stage = [&](int buf, int k0) {
#pragma unroll
    for (int r = 0; r < 4; ++r) {             // A: 128x64 = 1024 chunks
      int idx = r * 256 + tid;
      int m = idx >> 3, c8 = idx & 7;
      int src = c8 ^ (m & 7);
      __builtin_amdgcn_global_load_lds(
          (const __attribute__((address_space(1))) void*)(A + (row0 + m) * lda + k0 + src * 8),
          (__attribute__((address_space(3))) void*)(&As[buf][idx * 8]), 16, 0, 0);
    }
#pragma unroll
    for (int r = 0; r < 4; ++r) {             // B: 128x64 = 1024 chunks
      int idx = r * 256 + tid;
      int m = idx >> 3, c8 = idx & 7;
      int src = c8 ^ (m & 7);
      __builtin_amdgcn_global_load_lds(
          (const __attribute__((address_space(1))) void*)(Bw + (col0 + m) * ldb + k0 + src * 8),
          (__attribute__((address_space(3))) void*)(&Bs[buf][idx * 8]), 16, 0, 0);
    }
  };

  const int nk = K >> 6;
  stage(0, 0);
  for (int k = 0; k < nk; ++k) {
    if (k < nk - 1) {
      stage((k + 1) & 1, (k + 1) * 64);
      asm volatile("s_waitcnt vmcnt(8)" ::: "memory");   // cur's 8 loads done
    } else {
      asm volatile("s_waitcnt vmcnt(0)" ::: "memory");
    }
    __builtin_amdgcn_s_barrier();
    const short* Asc = As[k & 1];
    const short* Bsc = Bs[k & 1];
    s8v af[4][2], bf[4][2];
#pragma unroll
    for (int i = 0; i < 4; ++i)
#pragma unroll
      for (int hh = 0; hh < 2; ++hh)
        af[i][hh] = *(const s8v*)&Asc[(wm + i * 16 + r16) * 64 + ((hh * 4 + quad) ^ sw) * 8];
#pragma unroll
    for (int j = 0; j < 4; ++j)
#pragma unroll
      for (int hh = 0; hh < 2; ++hh)
        bf[j][hh] = *(const s8v*)&Bsc[(wn + j * 16 + r16) * 64 + ((hh * 4 + quad) ^ sw) * 8];
    __builtin_amdgcn_s_setprio(1);
#pragma unroll
    for (int hh = 0; hh < 2; ++hh)
#pragma unroll
      for (int i = 0; i < 4; ++i)
#pragma unroll
        for (int j = 0; j < 4; ++j)
          acc[i][j] = __builtin_amdgcn_mfma_f32_16x16x32_bf16(af[i][hh], bf[j][hh], acc[i][j], 0, 0, 0);
    __builtin_amdgcn_s_setprio(0);
    __builtin_amdgcn_s_barrier();
  }

#pragma unroll
  for (int i = 0; i < 4; ++i) {
    long rbase = row0 + wm + i * 16 + quad * 4;
#pragma unroll
    for (int j = 0; j < 4; ++j) {
      long c = col0 + wn + j * 16 + r16;
      float bv = bias ? bias[c] : 0.f;
#pragma unroll
      for (int rg = 0; rg < 4; ++rg)
        stc(&C[(rbase + rg) * ldc + c], (acc[i][j][rg] + bv) * scale);
    }
  }
}

// ---- Fused GRU step (Round-1 proven). Tile: 64 rows x 64 cols x 3 gates.
// Grid (8,64)=512 blocks (2/CU). BK=64, double-buffered LDS (64KB), counted
// vmcnt(8), XOR-swizzled chunks, setprio.
template <bool ENC>
__global__ __launch_bounds__(256) void gru_fused(
    const short* __restrict__ Aprev,  // (B,H) bf16 h_{t-1}
    const short* __restrict__ Whh,    // (3H,H) bf16
    const float* __restrict__ bhh,    // (3H)
    const short* __restrict__ xg,     // (B,3H) bf16 (decoder)
    const float* __restrict__ items_t,// encoder: &items[0][t][0], row stride 80
    const float* __restrict__ Wc,     // (3H,8)
    const float* __restrict__ bc,     // (3H)
    float* __restrict__ h,            // (B,H) fp32 master (in/out)
    short* __restrict__ hout)         // (B,H) bf16 history slice
{
  __shared__ short As[2][64 * 64];    // 16 KB
  __shared__ short Bs[2][192 * 64];   // 48 KB
  const int tid = threadIdx.x;
  const long row0 = (long)blockIdx.y * 64;
  const int col0 = blockIdx.x * 64;
  const int wave = tid >> 6, lane = tid & 63;
  const int r16 = lane & 15, quad = lane >> 4;
  const int sw = r16 & 7;

  f4v acc[3][4] = {};   // [gate][frag-row]

  auto stage = [&](int buf, int k0) {
#pragma unroll
    for (int r = 0; r < 2; ++r) {             // A: 64x64 = 512 chunks
      int idx = r * 256 + tid;
      int m = idx >> 3, c8 = idx & 7;
      int src = c8 ^ (m & 7);
      __builtin_amdgcn_global_load_lds(
          (const __attribute__((address_space(1))) void*)(Aprev + (row0 + m) * H_ + k0 + src * 8),
          (__attribute__((address_space(3))) void*)(&As[buf][idx * 8]), 16, 0, 0);
    }
#pragma unroll
    for (int r = 0; r < 6; ++r) {             // B: 192x64 = 1536 chunks
      int idx = r * 256 + tid;
      int m = idx >> 3, c8 = idx & 7;
      int src = c8 ^ (m & 7);
      int g = m >> 6, cc = m & 63;
      __builtin_amdgcn_global_load_lds(
          (const __attribute__((address_space(1))) void*)(Whh + ((long)g * H_ + col0 + cc) * H_ + k0 + src * 8),
          (__attribute__((address_space(3))) void*)(&Bs[buf][idx * 8]), 16, 0, 0);
    }
  };

  stage(0, 0);
  int cur = 0;
  for (int k = 0; k < 8; ++k) {
    if (k < 7) {
      stage(cur ^ 1, (k + 1) * 64);
      asm volatile("s_waitcnt vmcnt(8)" ::: "memory");   // cur's 8 loads done
    } else {
      asm volatile("s_waitcnt vmcnt(0)" ::: "memory");
    }
    __builtin_amdgcn_s_barrier();
    s8v af[4][2], bf[3][2];
#pragma unroll
    for (int i = 0; i < 4; ++i)
#pragma unroll
      for (int hh = 0; hh < 2; ++hh)
        af[i][hh] = *(const s8v*)&As[cur][(i * 16 + r16) * 64 + ((hh * 4 + quad) ^ sw) * 8];
#pragma unroll
    for (int g = 0; g < 3; ++g)
#pragma unroll
      for (int hh = 0; hh < 2; ++hh)
        bf[g][hh] = *(const s8v*)&Bs[cur][(g * 64 + wave * 16 + r16) * 64 + ((hh * 4 + quad) ^ sw) * 8];
    __builtin_amdgcn_s_setprio(1);
#pragma unroll
    for (int hh = 0; hh < 2; ++hh)
#pragma unroll
      for (int g = 0; g < 3; ++g)
#pragma unroll
        for (int i = 0; i < 4; ++i)
          acc[g][i] = __builtin_amdgcn_mfma_f32_16x16x32_bf16(af[i][hh], bf[g][hh], acc[g][i], 0, 0, 0);
    __builtin_amdgcn_s_setprio(0);
    __builtin_amdgcn_s_barrier();
    cur ^= 1;
  }

  // Column owned by this thread (C/D layout: col=lane&15, row=quad*4+reg).
  const int col = col0 + wave * 16 + r16;
  float wc[3][8], bcv[3];
  if (ENC) {
#pragma unroll
    for (int g = 0; g < 3; ++g) {
      const float* wr = Wc + ((long)g * H_ + col) * IN_;
#pragma unroll
      for (int j = 0; j < 8; ++j) wc[g][j] = wr[j];
      bcv[g] = bc[g * H_ + col];
    }
    // stage items rows into LDS (reuse As): 64 rows x 8 fp32
    float* itemS = (float*)As;
    int i2 = tid * 2;
    int m = i2 >> 3, j = i2 & 7;
    itemS[i2] = items_t[(row0 + m) * (L_ * IN_) + j];
    itemS[i2 + 1] = items_t[(row0 + m) * (L_ * IN_) + j + 1];
    __syncthreads();
  }
  float bhr = bhh[col], bhz = bhh[col + H_], bhn = bhh[col + 2 * H_];

#pragma unroll
  for (int i = 0; i < 4; ++i) {
#pragma unroll
    for (int rg = 0; rg < 4; ++rg) {
      int rl = i * 16 + quad * 4 + rg;
      long row = row0 + rl;
      float xr, xz, xn;
      if (ENC) {
        const float* it = (const float*)As + rl * 8;
        xr = bcv[0]; xz = bcv[1]; xn = bcv[2];
#pragma unroll
        for (int j = 0; j < 8; ++j) {
          float iv = it[j];
          xr += iv * wc[0][j];
          xz += iv * wc[1][j];
          xn += iv * wc[2][j];
        }
      } else {
        long gx = row * H3_ + col;
        xr = bf2f(xg[gx]); xz = bf2f(xg[gx + H_]); xn = bf2f(xg[gx + 2 * H_]);
      }
      float r = sig_fast(xr + acc[0][i][rg] + bhr);
      float z = sig_fast(xz + acc[1][i][rg] + bhz);
      float n = tanh_fast(xn + r * (acc[2][i][rg] + bhn));
      long hi = row * H_ + col;
      float hv = (1.f - z) * n + z * h[hi];
      h[hi] = hv;
      hout[hi] = f2bf(hv);
    }
  }
}

// ---- batched out_seq: one block per b. ew3/a4 arrive pre-scaled by LOG2E2,
// staged as f32 in LDS with conflict-free contiguous-quarter access:
// lane reads f4v at j=lane*4 and j=256+lane*4 (16B lane stride).
// tanh(x) = 1 - 2*rcp(exp2(x*LOG2E2)+1); "1" folded into svtot=sum(v2).
__global__ __launch_bounds__(256) void out_seq_all(
    const short* __restrict__ ew3,   // (Lenc, B, W) bf16, prescaled
    const short* __restrict__ a4,    // (Ldec, B, W) bf16, prescaled
    const float* __restrict__ v2,
    float* __restrict__ out)
{
  __shared__ float se[L_ * W_];   // 20 KB
  __shared__ float sa[L_ * W_];   // 20 KB
  const int b = blockIdx.x;
  const int tid = threadIdx.x;
  for (int i = tid; i < L_ * 128; i += 256) {
    int row = i >> 7, q = i & 127;
    s4v ev = *(const s4v*)(ew3 + ((long)row * B_ + b) * W_ + q * 4);
    s4v av = *(const s4v*)(a4 + ((long)row * B_ + b) * W_ + q * 4);
    f4v e, a;
#pragma unroll
    for (int j = 0; j < 4; ++j) { e[j] = bf2f(ev[j]); a[j] = bf2f(av[j]); }
    *(f4v*)(se + row * W_ + q * 4) = e;
    *(f4v*)(sa + row * W_ + q * 4) = a;
  }
  const int wave = tid >> 6, lane = tid & 63;
  float sv0[4], sv1[4], svtot = 0.f;
#pragma unroll
  for (int q = 0; q < 4; ++q) {
    float v = v2[lane * 4 + q];
    sv0[q] = -2.f * v; svtot += v;
    v = v2[256 + lane * 4 + q];
    sv1[q] = -2.f * v; svtot += v;
  }
#pragma unroll
  for (int off = 32; off; off >>= 1) svtot += __shfl_down(svtot, off, 64);
  svtot = __shfl(svtot, 0, 64);
  __syncthreads();

  int tprev = -1;
  f4v a0, a1;
#pragma unroll
  for (int pp = 0; pp < 25; ++pp) {
    int p = wave * 25 + pp;       // 100 (t,l) pairs over 4 waves
    int t = p / L_, l = p - t * L_;
    if (t != tprev) {             // wave-uniform branch; a-regs reused
      a0 = *(const f4v*)(sa + t * W_ + lane * 4);
      a1 = *(const f4v*)(sa + t * W_ + 256 + lane * 4);
      tprev = t;
    }
    f4v e0 = *(const f4v*)(se + l * W_ + lane * 4);
    f4v e1 = *(const f4v*)(se + l * W_ + 256 + lane * 4);
    float acc = 0.f;
#pragma unroll
    for (int q = 0; q < 4; ++q) {
      float x0 = __builtin_amdgcn_exp2f(e0[q] + a0[q]);
      acc += sv0[q] * __builtin_amdgcn_rcpf(x0 + 1.f);
      float x1 = __builtin_amdgcn_exp2f(e1[q] + a1[q]);
      acc += sv1[q] * __builtin_amdgcn_rcpf(x1 + 1.f);
    }
#pragma unroll
    for (int off = 32; off; off >>= 1) acc += __shfl_down(acc, off, 64);
    if (lane == 0) out[((long)b * L_ + t) * L_ + l] = svtot + acc;
  }
}

// ---- batched out_ori: one wave per (b,t). ----
__global__ __launch_bounds__(256) void out_ori_all(
    const short* __restrict__ dh,    // (Ldec, B, H) bf16
    const float* __restrict__ wori, const float* __restrict__ bori,
    float* __restrict__ out)
{
  int wid = (blockIdx.x * 256 + threadIdx.x) >> 6;   // b*L + t
  int lane = threadIdx.x & 63;
  int b = wid / L_, t = wid - b * L_;
  s8v hv = *(const s8v*)(dh + ((long)t * B_ + b) * H_ + lane * 8);
  float hf[8];
#pragma unroll
  for (int j = 0; j < 8; ++j) hf[j] = bf2f(hv[j]);
  float res[6];
#pragma unroll
  for (int o = 0; o < 6; ++o) {
    const float* wr = wori + (long)o * H3_ + H_ + lane * 8;
    float acc = 0.f;
#pragma unroll
    for (int j = 0; j < 8; ++j) acc += hf[j] * wr[j];
#pragma unroll
    for (int off = 32; off; off >>= 1) acc += __shfl_down(acc, off, 64);
    res[o] = acc;
  }
  if (lane == 0) {
    float* po = out + ORI_BASE + ((long)b * L_ + t) * 6;
#pragma unroll
    for (int o = 0; o < 6; ++o) po[o] = res[o] + bori[o];
  }
}

extern "C" void kernel_launch(void* const* d_in, const int* in_sizes, int n_in,
                              void* d_out, int out_size, void* d_ws, size_t ws_size,
                              hipStream_t stream)
{
  const float* items   = (const float*)d_in[0];
  const float* dec_in  = (const float*)d_in[1];
  const float* emb_w   = (const float*)d_in[2];
  const float* emb_b   = (const float*)d_in[3];
  const float* enc_wih = (const float*)d_in[4];
  const float* enc_whh = (const float*)d_in[5];
  const float* enc_bih = (const float*)d_in[6];
  const float* enc_bhh = (const float*)d_in[7];
  const float* dec_wih = (const float*)d_in[8];
  const float* dec_whh = (const float*)d_in[9];
  const float* dec_bih = (const float*)d_in[10];
  const float* dec_bhh = (const float*)d_in[11];
  const float* w3      = (const float*)d_in[14];
  const float* w4      = (const float*)d_in[15];
  const float* v2      = (const float*)d_in[20];
  const float* wori    = (const float*)d_in[23];
  const float* bori    = (const float*)d_in[24];
  float* out = (float*)d_out;

  char* ws = (char*)d_ws;
  size_t off = 0;
  auto alloc = [&](size_t bytes) { size_t o = off; off += (bytes + 255) & ~255UL; return o; };
  float* Wc       = (float*)(ws + alloc(H3_ * IN_ * 4));
  float* bc       = (float*)(ws + alloc(H3_ * 4));
  float* h        = (float*)(ws + alloc((size_t)B_ * H_ * 4));           // 8 MiB
  short* xgb      = (short*)(ws + alloc((size_t)B_ * H3_ * 2));          // 12 MiB
  short* enc_hist = (short*)(ws + alloc((size_t)11 * B_ * H_ * 2));      // 44 MiB
  short* dec_hist = (short*)(ws + alloc((size_t)L_ * B_ * H_ * 2));      // 40 MiB
  short* ew3      = (short*)(ws + alloc((size_t)L_ * B_ * W_ * 2));      // 40 MiB
  short* a4       = (short*)(ws + alloc((size_t)L_ * B_ * W_ * 2));      // 40 MiB
  short* whh_e    = (short*)(ws + alloc((size_t)H3_ * H_ * 2));
  short* whh_d    = (short*)(ws + alloc((size_t)H3_ * H_ * 2));
  short* wih_d    = (short*)(ws + alloc((size_t)H3_ * H_ * 2));
  short* w3b      = (short*)(ws + alloc((size_t)W_ * H_ * 2));
  short* w4b      = (short*)(ws + alloc((size_t)W_ * H_ * 2));
  short* decb     = (short*)(ws + alloc((size_t)B_ * H_ * 2));           // 4 MiB

  // ---- prep (one fused conversion dispatch) ----
  prep_all<<<(622592 + 255) / 256, 256, 0, stream>>>(
      enc_whh, whh_e, dec_whh, whh_d, dec_wih, wih_d,
      w3, w3b, w4, w4b, dec_in, decb);
  build_wc<<<384, 256, 0, stream>>>(enc_wih, emb_w, emb_b, enc_bih, Wc, bc);

  hipMemsetAsync(h, 0, (size_t)B_ * H_ * 4, stream);             // h0 = 0
  hipMemsetAsync(enc_hist, 0, (size_t)B_ * H_ * 2, stream);      // slice 0 = 0

  // xg_dec = dec_in @ dec_wih^T + dec_bih (fixed across decoder steps), bf16
  gemm_bf16<short><<<dim3(12, 32), 256, 0, stream>>>(
      decb, H_, wih_d, H_, dec_bih, xgb, H3_, H_, 1.f);

  // ---- Encoder recurrence: single fused kernel per step (xg inline) ----
  for (int t = 0; t < L_; ++t) {
    gru_fused<true><<<dim3(8, 64), 256, 0, stream>>>(
        enc_hist + (size_t)t * B_ * H_, whh_e, enc_bhh, nullptr,
        items + (size_t)t * IN_, Wc, bc, h,
        enc_hist + (size_t)(t + 1) * B_ * H_);
  }

  // ---- Decoder recurrence ----
  for (int t = 0; t < L_; ++t) {
    const short* prev = (t == 0) ? enc_hist + (size_t)10 * B_ * H_
                                 : dec_hist + (size_t)(t - 1) * B_ * H_;
    gru_fused<false><<<dim3(8, 64), 256, 0, stream>>>(
        prev, whh_d, dec_bhh, xgb, nullptr, nullptr, nullptr, h,
        dec_hist + (size_t)t * B_ * H_);
  }

  // ---- Batched epilogue (ew3/a4 prescaled by LOG2E2 for out_seq) ----
  gemm_bf16<short><<<dim3(4, 320), 256, 0, stream>>>(
      enc_hist + (size_t)B_ * H_, H_, w3b, H_, nullptr, ew3, W_, H_, LOG2E2);
  gemm_bf16<short><<<dim3(4, 320), 256, 0, stream>>>(
      dec_hist, H_, w4b, H_, nullptr, a4, W_, H_, LOG2E2);
  out_seq_all<<<B_, 256, 0, stream>>>(ew3, a4, v2, out);
  out_ori_all<<<(B_ * L_) / 4, 256, 0, stream>>>(dec_hist, wori, bori, out);
}